// Round 1
// baseline (92.875 us; speedup 1.0000x reference)
//
#include <hip/hip_runtime.h>
#include <math.h>

#define N_ROWS 2048
#define D_DIM 512
#define P_DIM 10

__device__ inline float wave_reduce_f(float v) {
#pragma unroll
  for (int off = 32; off > 0; off >>= 1) v += __shfl_down(v, off, 64);
  return v;
}

__device__ inline double wave_reduce_d(double v) {
#pragma unroll
  for (int off = 32; off > 0; off >>= 1) v += __shfl_down(v, off, 64);
  return v;
}

// K1: wave-per-row. Computes post_cm[p][row] = z[row,:]@proj[:,p] and
// prior_cm[p][row] = (gmm_noise[row,:]/max(||row||,eps))@proj[:,p].
// proj staged transposed in LDS as [p][k] so lane-stride-1 LDS reads are
// conflict-free (2 lanes/bank = free on gfx950).
__global__ __launch_bounds__(256) void rc_proj_kernel(
    const float* __restrict__ z, const float* __restrict__ g,
    const float* __restrict__ proj, float* __restrict__ post_cm,
    float* __restrict__ prior_cm) {
  __shared__ float pl[P_DIM * D_DIM];  // [p][k], 20 KiB
  for (int i = threadIdx.x; i < P_DIM * D_DIM; i += 256) {
    int k = i / P_DIM, p = i - k * P_DIM;
    pl[p * D_DIM + k] = proj[i];
  }
  __syncthreads();
  const int wave = threadIdx.x >> 6, lane = threadIdx.x & 63;
  const int row = blockIdx.x * 4 + wave;
  const float* zr = z + (size_t)row * D_DIM;
  const float* gr = g + (size_t)row * D_DIM;
  float zv[8], gv[8];
#pragma unroll
  for (int m = 0; m < 8; ++m) {  // coalesced: lane-stride-1, 4B/lane
    zv[m] = zr[m * 64 + lane];
    gv[m] = gr[m * 64 + lane];
  }
  float n2 = 0.f;
#pragma unroll
  for (int m = 0; m < 8; ++m) n2 += gv[m] * gv[m];
  float az[P_DIM], ag[P_DIM];
#pragma unroll
  for (int p = 0; p < P_DIM; ++p) { az[p] = 0.f; ag[p] = 0.f; }
#pragma unroll
  for (int m = 0; m < 8; ++m) {
#pragma unroll
    for (int p = 0; p < P_DIM; ++p) {
      float w = pl[p * D_DIM + m * 64 + lane];
      az[p] += zv[m] * w;
      ag[p] += gv[m] * w;
    }
  }
#pragma unroll
  for (int p = 0; p < P_DIM; ++p) {
    az[p] = wave_reduce_f(az[p]);
    ag[p] = wave_reduce_f(ag[p]);
  }
  n2 = wave_reduce_f(n2);
  if (lane == 0) {
    float inv = 1.f / fmaxf(sqrtf(n2), 1e-12f);
    for (int p = 0; p < P_DIM; ++p) {
      post_cm[p * N_ROWS + row] = az[p];
      prior_cm[p * N_ROWS + row] = ag[p] * inv;
    }
  }
}

// K2: bitonic sort of one 2048-element column in LDS. 20 blocks (10 post
// columns, 10 prior columns), 1024 threads, ascending, in-place.
__global__ __launch_bounds__(1024) void rc_sort_kernel(
    float* __restrict__ post_cm, float* __restrict__ prior_cm) {
  float* buf = (blockIdx.x < P_DIM) ? post_cm + blockIdx.x * N_ROWS
                                    : prior_cm + (blockIdx.x - P_DIM) * N_ROWS;
  __shared__ float s[N_ROWS];
  const int tid = threadIdx.x;
  s[tid] = buf[tid];
  s[tid + 1024] = buf[tid + 1024];
  for (unsigned k = 2; k <= N_ROWS; k <<= 1) {
    for (unsigned j = k >> 1; j > 0; j >>= 1) {
      __syncthreads();
#pragma unroll
      for (int t = 0; t < 2; ++t) {
        unsigned idx = (unsigned)tid + (unsigned)t * 1024u;
        unsigned ixj = idx ^ j;
        if (ixj > idx) {
          float x = s[idx], y = s[ixj];
          bool up = (idx & k) == 0;
          if (up ? (x > y) : (x < y)) { s[idx] = y; s[ixj] = x; }
        }
      }
    }
  }
  __syncthreads();
  buf[tid] = s[tid];
  buf[tid + 1024] = s[tid + 1024];
}

// K3: per-(column p, variant) closed-form statistics in f64.
// gw*N^2 = 2N*Ss2 + 2*Ss^2 - 8*(Ssa*Sa - Ssb*Sb) + 4*(Sa2^2 - 2*Sab^2 + Sb2^2)
// where s_i = a_i^2 - b_i^2. variant 1 uses b reversed (prior2 = prior1[::-1]).
__global__ __launch_bounds__(256) void rc_stats_kernel(
    const float* __restrict__ post_cm, const float* __restrict__ prior_cm,
    float* __restrict__ fgw) {
  const int p = blockIdx.x % P_DIM;
  const int variant = blockIdx.x / P_DIM;
  const float* a = post_cm + p * N_ROWS;
  const float* b = prior_cm + p * N_ROWS;
  double S[10];
#pragma unroll
  for (int t = 0; t < 10; ++t) S[t] = 0.0;
  for (int i = threadIdx.x; i < N_ROWS; i += 256) {
    double av = (double)a[i];
    double bv = (double)(variant ? b[N_ROWS - 1 - i] : b[i]);
    double a2 = av * av, b2 = bv * bv;
    double s = a2 - b2;
    S[0] += s * s;
    S[1] += s;
    S[2] += s * av;
    S[3] += av;
    S[4] += s * bv;
    S[5] += bv;
    S[6] += a2;
    S[7] += av * bv;
    S[8] += b2;
    double d = av - bv;
    S[9] += d * d;
  }
#pragma unroll
  for (int t = 0; t < 10; ++t) S[t] = wave_reduce_d(S[t]);
  __shared__ double sm[4][10];
  const int wave = threadIdx.x >> 6, lane = threadIdx.x & 63;
  if (lane == 0) {
#pragma unroll
    for (int t = 0; t < 10; ++t) sm[wave][t] = S[t];
  }
  __syncthreads();
  if (threadIdx.x == 0) {
    double T[10];
#pragma unroll
    for (int t = 0; t < 10; ++t)
      T[t] = sm[0][t] + sm[1][t] + sm[2][t] + sm[3][t];
    const double nn = (double)N_ROWS;
    double gw = (2.0 * nn * T[0] + 2.0 * T[1] * T[1]
                 - 8.0 * (T[2] * T[3] - T[4] * T[5])
                 + 4.0 * (T[6] * T[6] - 2.0 * T[7] * T[7] + T[8] * T[8]))
                / (nn * nn);
    double w = T[9];
    fgw[blockIdx.x] = (float)(0.9 * w + 0.1 * gw);
  }
}

// K4: out = mean_p min(fgw1[p], fgw2[p])
__global__ void rc_final_kernel(const float* __restrict__ fgw,
                                float* __restrict__ out) {
  if (threadIdx.x == 0 && blockIdx.x == 0) {
    float s = 0.f;
    for (int p = 0; p < P_DIM; ++p) s += fminf(fgw[p], fgw[P_DIM + p]);
    out[0] = s * (1.f / P_DIM);
  }
}

extern "C" void kernel_launch(void* const* d_in, const int* in_sizes, int n_in,
                              void* d_out, int out_size, void* d_ws,
                              size_t ws_size, hipStream_t stream) {
  const float* z = (const float*)d_in[0];
  const float* g = (const float*)d_in[1];
  const float* proj = (const float*)d_in[2];
  float* out = (float*)d_out;
  float* post_cm = (float*)d_ws;                      // 2048*10 f32
  float* prior_cm = post_cm + N_ROWS * P_DIM;         // 2048*10 f32
  float* fgw = prior_cm + N_ROWS * P_DIM;             // 20 f32

  rc_proj_kernel<<<N_ROWS / 4, 256, 0, stream>>>(z, g, proj, post_cm, prior_cm);
  rc_sort_kernel<<<2 * P_DIM, 1024, 0, stream>>>(post_cm, prior_cm);
  rc_stats_kernel<<<2 * P_DIM, 256, 0, stream>>>(post_cm, prior_cm, fgw);
  rc_final_kernel<<<1, 64, 0, stream>>>(fgw, out);
}